// Round 1
// baseline (2711.633 us; speedup 1.0000x reference)
//
#include <hip/hip_runtime.h>
#include <math.h>

#define TOK 4096
#define HD 512

__device__ __forceinline__ float gelu_f(float x) {
    // jax.nn.gelu(approximate=False): x * 0.5 * (1 + erf(x/sqrt(2)))
    return 0.5f * x * (1.0f + erff(x * 0.70710678118654752f));
}

// ------------------------------------------------------------------
// Generic 64x64 fp32 tiled GEMM: C[M,N] = act(A[M,K] @ B[K,N] + bias)
// grid = (N/64, M/64), block = 256.  BK=16, each thread 4x4 outputs.
// ------------------------------------------------------------------
template<int ACT>
__global__ __launch_bounds__(256)
void gemm64(const float* __restrict__ A, int lda,
            const float* __restrict__ B, int ldb,
            const float* __restrict__ bias,
            float* __restrict__ C, int ldc, int K)
{
    __shared__ float As[16][68];   // [k][m], padded stride 68 (16B-aligned, conflict-free)
    __shared__ float Bs[16][68];   // [k][n]
    const int tid = threadIdx.x;
    const int tx = tid & 15, ty = tid >> 4;
    const int m0 = blockIdx.y << 6, n0 = blockIdx.x << 6;
    const int lm = tid >> 2, lk = (tid & 3) << 2;   // A tile load: 64 rows x 16 k
    const int bk = tid >> 4, bn = (tid & 15) << 2;  // B tile load: 16 k x 64 n

    float acc[4][4] = {};
    const float* Ap = A + (size_t)(m0 + lm) * lda + lk;
    const float* Bp = B + (size_t)bk * ldb + n0 + bn;

    for (int k0 = 0; k0 < K; k0 += 16) {
        float4 av = *(const float4*)(Ap + k0);
        float4 bv = *(const float4*)(Bp + (size_t)k0 * ldb);
        As[lk + 0][lm] = av.x; As[lk + 1][lm] = av.y;
        As[lk + 2][lm] = av.z; As[lk + 3][lm] = av.w;
        *(float4*)&Bs[bk][bn] = bv;
        __syncthreads();
        #pragma unroll
        for (int kk = 0; kk < 16; ++kk) {
            float4 a = *(const float4*)&As[kk][ty << 2];
            float4 b = *(const float4*)&Bs[kk][tx << 2];
            float ar[4] = {a.x, a.y, a.z, a.w};
            float br[4] = {b.x, b.y, b.z, b.w};
            #pragma unroll
            for (int i = 0; i < 4; ++i)
                #pragma unroll
                for (int j = 0; j < 4; ++j)
                    acc[i][j] = fmaf(ar[i], br[j], acc[i][j]);
        }
        __syncthreads();
    }
    #pragma unroll
    for (int i = 0; i < 4; ++i) {
        const int m = m0 + (ty << 2) + i;
        float4 o;
        #pragma unroll
        for (int j = 0; j < 4; ++j) {
            const int n = n0 + (tx << 2) + j;
            float v = acc[i][j] + bias[n];
            if (ACT) v = gelu_f(v);
            ((float*)&o)[j] = v;
        }
        *(float4*)&C[(size_t)m * ldc + n0 + (tx << 2)] = o;
    }
}

// ------------------------------------------------------------------
// Expert hidden: h[e][m][k] = route_w[m][e] * gelu(x[m]@ew1[e] + eb1[e])
// grid = (512/64, Mc/64, 8); x is the chunk base, rw = route_w + m0chunk*8
// ------------------------------------------------------------------
__global__ __launch_bounds__(256)
void expert_h_gemm(const float* __restrict__ x,
                   const float* __restrict__ ew1,
                   const float* __restrict__ eb1,
                   const float* __restrict__ rw,
                   float* __restrict__ h, int Mc)
{
    __shared__ float As[16][68];
    __shared__ float Bs[16][68];
    const int e = blockIdx.z;
    const float* B = ew1 + ((size_t)e << 18);      // e*512*512
    const float* bias = eb1 + (e << 9);
    float* C = h + (((size_t)e * Mc) << 9);
    const int tid = threadIdx.x;
    const int tx = tid & 15, ty = tid >> 4;
    const int m0 = blockIdx.y << 6, n0 = blockIdx.x << 6;
    const int lm = tid >> 2, lk = (tid & 3) << 2;
    const int bk = tid >> 4, bn = (tid & 15) << 2;

    float acc[4][4] = {};
    const float* Ap = x + (((size_t)(m0 + lm)) << 9) + lk;
    const float* Bp = B + (((size_t)bk) << 9) + n0 + bn;

    for (int k0 = 0; k0 < 512; k0 += 16) {
        float4 av = *(const float4*)(Ap + k0);
        float4 bv = *(const float4*)(Bp + ((size_t)k0 << 9));
        As[lk + 0][lm] = av.x; As[lk + 1][lm] = av.y;
        As[lk + 2][lm] = av.z; As[lk + 3][lm] = av.w;
        *(float4*)&Bs[bk][bn] = bv;
        __syncthreads();
        #pragma unroll
        for (int kk = 0; kk < 16; ++kk) {
            float4 a = *(const float4*)&As[kk][ty << 2];
            float4 b = *(const float4*)&Bs[kk][tx << 2];
            float ar[4] = {a.x, a.y, a.z, a.w};
            float br[4] = {b.x, b.y, b.z, b.w};
            #pragma unroll
            for (int i = 0; i < 4; ++i)
                #pragma unroll
                for (int j = 0; j < 4; ++j)
                    acc[i][j] = fmaf(ar[i], br[j], acc[i][j]);
        }
        __syncthreads();
    }
    #pragma unroll
    for (int i = 0; i < 4; ++i) {
        const int m = m0 + (ty << 2) + i;
        const float scale = rw[(m << 3) + e];
        float4 o;
        #pragma unroll
        for (int j = 0; j < 4; ++j) {
            const int n = n0 + (tx << 2) + j;
            ((float*)&o)[j] = gelu_f(acc[i][j] + bias[n]) * scale;
        }
        *(float4*)&C[((size_t)m << 9) + n0 + (tx << 2)] = o;
    }
}

// ------------------------------------------------------------------
// Mix: mixed[m][n] = sum_e rw[m][e]*(h_e[m]@ew2[e] + eb2[e])
// h already pre-scaled by rw -> single GEMM with K=4096 over e-blocked A.
// B = ew2 flattened is exactly [4096,512] row-major. Bias term added in epilogue.
// grid = (512/64, Mc/64)
// ------------------------------------------------------------------
__global__ __launch_bounds__(256)
void mix_gemm(const float* __restrict__ h,
              const float* __restrict__ ew2,
              const float* __restrict__ eb2,
              const float* __restrict__ rw,
              float* __restrict__ C, int Mc)
{
    __shared__ float As[16][68];
    __shared__ float Bs[16][68];
    const int tid = threadIdx.x;
    const int tx = tid & 15, ty = tid >> 4;
    const int m0 = blockIdx.y << 6, n0 = blockIdx.x << 6;
    const int lm = tid >> 2, lk = (tid & 3) << 2;
    const int bk = tid >> 4, bn = (tid & 15) << 2;

    float acc[4][4] = {};
    const float* Ap = h + (((size_t)(m0 + lm)) << 9) + lk;
    const float* Bp = ew2 + (((size_t)bk) << 9) + n0 + bn;

    for (int k0 = 0; k0 < 4096; k0 += 16) {
        const int e = k0 >> 9, koff = k0 & 511;
        float4 av = *(const float4*)(Ap + (((size_t)e * Mc) << 9) + koff);
        float4 bv = *(const float4*)(Bp + ((size_t)k0 << 9));
        As[lk + 0][lm] = av.x; As[lk + 1][lm] = av.y;
        As[lk + 2][lm] = av.z; As[lk + 3][lm] = av.w;
        *(float4*)&Bs[bk][bn] = bv;
        __syncthreads();
        #pragma unroll
        for (int kk = 0; kk < 16; ++kk) {
            float4 a = *(const float4*)&As[kk][ty << 2];
            float4 b = *(const float4*)&Bs[kk][tx << 2];
            float ar[4] = {a.x, a.y, a.z, a.w};
            float br[4] = {b.x, b.y, b.z, b.w};
            #pragma unroll
            for (int i = 0; i < 4; ++i)
                #pragma unroll
                for (int j = 0; j < 4; ++j)
                    acc[i][j] = fmaf(ar[i], br[j], acc[i][j]);
        }
        __syncthreads();
    }
    #pragma unroll
    for (int i = 0; i < 4; ++i) {
        const int m = m0 + (ty << 2) + i;
        float rwr[8];
        #pragma unroll
        for (int e = 0; e < 8; ++e) rwr[e] = rw[(m << 3) + e];
        float4 o;
        #pragma unroll
        for (int j = 0; j < 4; ++j) {
            const int n = n0 + (tx << 2) + j;
            float v = acc[i][j];
            #pragma unroll
            for (int e = 0; e < 8; ++e) v = fmaf(rwr[e], eb2[(e << 9) + n], v);
            ((float*)&o)[j] = v;
        }
        *(float4*)&C[((size_t)m << 9) + n0 + (tx << 2)] = o;
    }
}

// ------------------------------------------------------------------
// Router: logits = t @ rw2 + rb2 (N=8), softmax -> route_w [TOK,8]
// One wave per token; rw2 staged in LDS padded to stride 9 (conflict-free).
// ------------------------------------------------------------------
__global__ __launch_bounds__(256)
void router_kernel(const float* __restrict__ t,
                   const float* __restrict__ rw2,
                   const float* __restrict__ rb2,
                   float* __restrict__ route_w)
{
    __shared__ float s[512 * 9];
    const int tid = threadIdx.x;
    for (int idx = tid; idx < 4096; idx += 256)
        s[(idx >> 3) * 9 + (idx & 7)] = rw2[idx];
    __syncthreads();
    const int lane = tid & 63;
    const int tok = (blockIdx.x << 2) + (tid >> 6);
    const float* tp = t + ((size_t)tok << 9);
    float acc[8] = {};
    #pragma unroll
    for (int kq = 0; kq < 8; ++kq) {
        const int k = (kq << 6) + lane;
        const float tv = tp[k];
        #pragma unroll
        for (int e = 0; e < 8; ++e)
            acc[e] = fmaf(tv, s[k * 9 + e], acc[e]);
    }
    #pragma unroll
    for (int e = 0; e < 8; ++e)
        #pragma unroll
        for (int off = 32; off; off >>= 1)
            acc[e] += __shfl_xor(acc[e], off, 64);
    float mx = -1e30f;
    #pragma unroll
    for (int e = 0; e < 8; ++e) { acc[e] += rb2[e]; mx = fmaxf(mx, acc[e]); }
    float sum = 0.f;
    #pragma unroll
    for (int e = 0; e < 8; ++e) { acc[e] = expf(acc[e] - mx); sum += acc[e]; }
    const float inv = 1.0f / sum;
    if (lane == 0) {
        #pragma unroll
        for (int e = 0; e < 8; ++e) route_w[(tok << 3) + e] = acc[e] * inv;
    }
}

// ------------------------------------------------------------------
// Score: mlog[tok][mod] = u[tok] . sw2 + sb2   (one wave per token)
// ------------------------------------------------------------------
__global__ __launch_bounds__(256)
void score_kernel(const float* __restrict__ u,
                  const float* __restrict__ sw2,
                  const float* __restrict__ sb2,
                  float* __restrict__ mlog, int mod)
{
    const int tid = threadIdx.x;
    const int lane = tid & 63;
    const int tok = (blockIdx.x << 2) + (tid >> 6);
    const float* up = u + ((size_t)tok << 9);
    float acc = 0.f;
    #pragma unroll
    for (int kq = 0; kq < 8; ++kq) {
        const int k = (kq << 6) + lane;
        acc = fmaf(up[k], sw2[k], acc);
    }
    #pragma unroll
    for (int off = 32; off; off >>= 1) acc += __shfl_xor(acc, off, 64);
    if (lane == 0) mlog[(tok << 2) + mod] = acc + sb2[0];
}

// ------------------------------------------------------------------
// Final: top-2 over 4 modality logits, masked softmax, consensus blend,
// LayerNorm. One block (256 thr) per token; each thread 2 h-elements.
// ------------------------------------------------------------------
__global__ __launch_bounds__(256)
void final_kernel(const float* __restrict__ mixedb,
                  const float* __restrict__ mlog,
                  const float* __restrict__ g,
                  const float* __restrict__ bta,
                  float* __restrict__ out)
{
    const int tok = blockIdx.x, tid = threadIdx.x;
    float v[4];
    #pragma unroll
    for (int m = 0; m < 4; ++m) v[m] = mlog[(tok << 2) + m];
    // top-2, ties -> lowest index (matches lax.top_k)
    int i1 = 0;
    #pragma unroll
    for (int m = 1; m < 4; ++m) if (v[m] > v[i1]) i1 = m;
    int i2 = (i1 == 0) ? 1 : 0;
    for (int m = i2 + 1; m < 4; ++m) if (m != i1 && v[m] > v[i2]) i2 = m;
    const float e2 = expf(v[i2] - v[i1]);
    const float winv = 1.0f / (1.0f + e2);
    const float w1 = winv, w2 = e2 * winv;
    const float* p1 = mixedb + (((size_t)i1 * TOK + tok) << 9);
    const float* p2 = mixedb + (((size_t)i2 * TOK + tok) << 9);
    const int h0 = tid, h1 = tid + 256;
    const float c0 = w1 * p1[h0] + w2 * p2[h0];
    const float c1 = w1 * p1[h1] + w2 * p2[h1];
    float s = c0 + c1, sq = c0 * c0 + c1 * c1;
    #pragma unroll
    for (int off = 32; off; off >>= 1) {
        s += __shfl_xor(s, off, 64);
        sq += __shfl_xor(sq, off, 64);
    }
    __shared__ float red[8];
    const int wv = tid >> 6, ln = tid & 63;
    if (ln == 0) { red[wv] = s; red[4 + wv] = sq; }
    __syncthreads();
    s = red[0] + red[1] + red[2] + red[3];
    sq = red[4] + red[5] + red[6] + red[7];
    const float mu = s * (1.0f / 512.0f);
    const float var = sq * (1.0f / 512.0f) - mu * mu;
    const float r = 1.0f / sqrtf(var + 1e-5f);
    out[((size_t)tok << 9) + h0] = (c0 - mu) * r * g[h0] + bta[h0];
    out[((size_t)tok << 9) + h1] = (c1 - mu) * r * g[h1] + bta[h1];
}

extern "C" void kernel_launch(void* const* d_in, const int* in_sizes, int n_in,
                              void* d_out, int out_size, void* d_ws, size_t ws_size,
                              hipStream_t stream)
{
    (void)in_sizes; (void)n_in; (void)out_size;
    const float* ew1  = (const float*)d_in[12];
    const float* eb1  = (const float*)d_in[13];
    const float* ew2  = (const float*)d_in[14];
    const float* eb2  = (const float*)d_in[15];
    const float* rw1  = (const float*)d_in[16];
    const float* rb1  = (const float*)d_in[17];
    const float* rw2  = (const float*)d_in[18];
    const float* rb2  = (const float*)d_in[19];
    const float* sw1  = (const float*)d_in[20];
    const float* sb1  = (const float*)d_in[21];
    const float* sw2  = (const float*)d_in[22];
    const float* sb2  = (const float*)d_in[23];
    const float* ln_g = (const float*)d_in[24];
    const float* ln_b = (const float*)d_in[25];
    const int KD[4] = {1024, 64, 768, 512};

    // workspace layout (floats)
    float* ws      = (float*)d_ws;
    float* x       = ws;                             // TOK*HD
    float* mixedb  = x + (size_t)TOK * HD;           // 4*TOK*HD
    float* route_w = mixedb + (size_t)4 * TOK * HD;  // TOK*8
    float* mlog    = route_w + (size_t)TOK * 8;      // TOK*4
    float* scratch = mlog + (size_t)TOK * 4;         // max(TOK*HD, Mc*8*HD): t/u/h

    // choose expert-chunk Mc so everything fits ws_size
    const size_t capf = ws_size / sizeof(float);
    const size_t fixedf = (size_t)TOK * HD * 5 + (size_t)TOK * 12;
    int Mc = 512;
    const int cands[4] = {4096, 2048, 1024, 512};
    for (int ci = 0; ci < 4; ++ci) {
        size_t sf = (size_t)cands[ci] * 8 * HD;
        if (sf < (size_t)TOK * HD) sf = (size_t)TOK * HD;
        if (fixedf + sf <= capf) { Mc = cands[ci]; break; }
    }

    for (int mod = 0; mod < 4; ++mod) {
        const float* feat = (const float*)d_in[mod * 3 + 0];
        const float* pw   = (const float*)d_in[mod * 3 + 1];
        const float* pb   = (const float*)d_in[mod * 3 + 2];
        float* mixm = mixedb + (size_t)mod * TOK * HD;

        // x = feat @ pw + pb
        gemm64<0><<<dim3(HD / 64, TOK / 64), 256, 0, stream>>>(
            feat, KD[mod], pw, HD, pb, x, HD, KD[mod]);
        // t = gelu(x @ rw1 + rb1)   (t lives in scratch)
        gemm64<1><<<dim3(HD / 64, TOK / 64), 256, 0, stream>>>(
            x, HD, rw1, HD, rb1, scratch, HD, HD);
        // route_w = softmax(t @ rw2 + rb2)
        router_kernel<<<dim3(TOK / 4), 256, 0, stream>>>(scratch, rw2, rb2, route_w);
        // experts, chunked over tokens
        for (int m0 = 0; m0 < TOK; m0 += Mc) {
            expert_h_gemm<<<dim3(HD / 64, Mc / 64, 8), 256, 0, stream>>>(
                x + ((size_t)m0 << 9), ew1, eb1, route_w + ((size_t)m0 << 3), scratch, Mc);
            mix_gemm<<<dim3(HD / 64, Mc / 64), 256, 0, stream>>>(
                scratch, ew2, eb2, route_w + ((size_t)m0 << 3),
                mixm + ((size_t)m0 << 9), Mc);
        }
        // u = gelu(mixed @ sw1 + sb1)   (u lives in scratch)
        gemm64<1><<<dim3(HD / 64, TOK / 64), 256, 0, stream>>>(
            mixm, HD, sw1, HD, sb1, scratch, HD, HD);
        // mlog[:,mod] = u @ sw2 + sb2
        score_kernel<<<dim3(TOK / 4), 256, 0, stream>>>(scratch, sw2, sb2, mlog, mod);
    }
    final_kernel<<<dim3(TOK), 256, 0, stream>>>(mixedb, mlog, ln_g, ln_b, (float*)d_out);
}

// Round 2
// 1694.282 us; speedup vs baseline: 1.6005x; 1.6005x over previous
//
#include <hip/hip_runtime.h>
#include <math.h>

#define TOK 4096
#define HD 512

typedef _Float16 f16x8 __attribute__((ext_vector_type(8)));
typedef float f32x4 __attribute__((ext_vector_type(4)));

__device__ __forceinline__ float gelu_f(float x) {
    return 0.5f * x * (1.0f + erff(x * 0.70710678118654752f));
}

__device__ __forceinline__ void gload16(const void* g, void* l) {
    __builtin_amdgcn_global_load_lds((const __attribute__((address_space(1))) void*)g,
                                     (__attribute__((address_space(3))) void*)l, 16, 0, 0);
}

__device__ __forceinline__ void split2(float v, _Float16& h, _Float16& l) {
    h = (_Float16)v;
    l = (_Float16)(v - (float)h);
}

// ------------------------------------------------------------------
// fp32 -> (hi,lo) fp16 elementwise, 8 elems/thread, same layout
// ------------------------------------------------------------------
__global__ __launch_bounds__(256)
void split_x_kernel(const float* __restrict__ in, _Float16* __restrict__ hi,
                    _Float16* __restrict__ lo)
{
    const size_t idx = (size_t)blockIdx.x * 256 + threadIdx.x;
    const float4 v0 = *(const float4*)(in + idx * 8);
    const float4 v1 = *(const float4*)(in + idx * 8 + 4);
    float vv[8] = {v0.x, v0.y, v0.z, v0.w, v1.x, v1.y, v1.z, v1.w};
    f16x8 h, l;
    #pragma unroll
    for (int j = 0; j < 8; ++j) {
        _Float16 a, b; split2(vv[j], a, b);
        h[j] = a; l[j] = b;
    }
    *(f16x8*)(hi + idx * 8) = h;
    *(f16x8*)(lo + idx * 8) = l;
}

// ------------------------------------------------------------------
// Expert weight prep: in [e][k=512][n=512] fp32 row-major ->
// out hi/lo fp16 in fragment layout [e][kbG=64][n=512][8] (8 = k-minor)
// one thread per (e,kbG,n) chunk; grid 1024 x 256
// ------------------------------------------------------------------
__global__ __launch_bounds__(256)
void split_w_kernel(const float* __restrict__ w, _Float16* __restrict__ hi,
                    _Float16* __restrict__ lo)
{
    const int idx = blockIdx.x * 256 + threadIdx.x;  // [0, 8*64*512)
    const int e = idx >> 15, kbG = (idx >> 9) & 63, n = idx & 511;
    const float* src = w + (((size_t)e * 512 + kbG * 8) << 9) + n;
    f16x8 h, l;
    #pragma unroll
    for (int j = 0; j < 8; ++j) {
        const float v = src[(size_t)j << 9];
        _Float16 a, b; split2(v, a, b);
        h[j] = a; l[j] = b;
    }
    *(f16x8*)(hi + (size_t)idx * 8) = h;
    *(f16x8*)(lo + (size_t)idx * 8) = l;
}

// ------------------------------------------------------------------
// Expert hidden, split-fp16 MFMA:
// h[e][m][n] = rw[m][e] * gelu(sum_k x[m][k]*ew1[e][k][n] + eb1[e][n])
// BM=128, BN=128, BK=32. 4 waves in 2x2, each wave 64x64 (4x4 frags).
// grid = (4, Mc/128, 8)
// ------------------------------------------------------------------
__global__ __launch_bounds__(256)
void expert_h_mfma(const _Float16* __restrict__ xh, const _Float16* __restrict__ xl,
                   const _Float16* __restrict__ w1h, const _Float16* __restrict__ w1l,
                   const float* __restrict__ eb1, const float* __restrict__ rw,
                   _Float16* __restrict__ hh, _Float16* __restrict__ hl, int Mc)
{
    __shared__ _Float16 Ah[4096], Al[4096], Bh[4096], Bl[4096];
    const int tid = threadIdx.x;
    const int l = tid & 63, w = tid >> 6;
    const int e = blockIdx.z;
    const int m0 = blockIdx.y << 7, n0 = blockIdx.x << 7;
    const int wm = w >> 1, wn = w & 1;
    const int kb = l >> 4, lr = l & 15;

    int aoff[4], boff[4];
    #pragma unroll
    for (int i = 0; i < 4; ++i) {
        aoff[i] = (kb * 128 + wm * 64 + i * 16 + lr) * 8;
        boff[i] = (kb * 128 + wn * 64 + i * 16 + lr) * 8;
    }
    f32x4 acc[4][4];
    #pragma unroll
    for (int i = 0; i < 4; ++i)
        #pragma unroll
        for (int j = 0; j < 4; ++j)
            acc[i][j] = (f32x4){0.f, 0.f, 0.f, 0.f};

    const _Float16* w1he = w1h + ((size_t)e << 18);  // e*64*512*8
    const _Float16* w1le = w1l + ((size_t)e << 18);
    const int wbase = tid & 192;  // wave id * 64, wave-uniform

    for (int k0 = 0; k0 < 512; k0 += 32) {
        #pragma unroll
        for (int j = 0; j < 2; ++j) {
            const int c = (j << 8) + tid;
            const int ckb = c >> 7, cr = c & 127;
            const int lofs = ((j << 8) + wbase) * 8;
            const size_t ga = ((size_t)(m0 + cr) << 9) + k0 + ckb * 8;
            gload16(xh + ga, (void*)(Ah + lofs));
            gload16(xl + ga, (void*)(Al + lofs));
            const size_t gb = ((size_t)(((k0 >> 3) + ckb) << 9) + n0 + cr) * 8;
            gload16(w1he + gb, (void*)(Bh + lofs));
            gload16(w1le + gb, (void*)(Bl + lofs));
        }
        __syncthreads();
        f16x8 fah[4], fal[4], fbh[4], fbl[4];
        #pragma unroll
        for (int i = 0; i < 4; ++i) {
            fah[i] = *(const f16x8*)(Ah + aoff[i]);
            fal[i] = *(const f16x8*)(Al + aoff[i]);
            fbh[i] = *(const f16x8*)(Bh + boff[i]);
            fbl[i] = *(const f16x8*)(Bl + boff[i]);
        }
        #pragma unroll
        for (int i = 0; i < 4; ++i)
            #pragma unroll
            for (int j = 0; j < 4; ++j) {
                acc[i][j] = __builtin_amdgcn_mfma_f32_16x16x32_f16(fah[i], fbh[j], acc[i][j], 0, 0, 0);
                acc[i][j] = __builtin_amdgcn_mfma_f32_16x16x32_f16(fah[i], fbl[j], acc[i][j], 0, 0, 0);
                acc[i][j] = __builtin_amdgcn_mfma_f32_16x16x32_f16(fal[i], fbh[j], acc[i][j], 0, 0, 0);
            }
        __syncthreads();
    }
    #pragma unroll
    for (int i = 0; i < 4; ++i)
        #pragma unroll
        for (int j = 0; j < 4; ++j)
            #pragma unroll
            for (int r = 0; r < 4; ++r) {
                const int m = m0 + wm * 64 + i * 16 + (l >> 4) * 4 + r;
                const int n = n0 + wn * 64 + j * 16 + lr;
                const float v = gelu_f(acc[i][j][r] + eb1[(e << 9) + n]) * rw[(m << 3) + e];
                _Float16 vh, vl; split2(v, vh, vl);
                const size_t o = (((size_t)e * Mc + m) << 9) + n;
                hh[o] = vh; hl[o] = vl;
            }
}

// ------------------------------------------------------------------
// Mix, split-fp16 MFMA: mixed[m][n] = sum_{e,k} h[e][m][k]*ew2[e][k][n]
//                                     + sum_e rw[m][e]*eb2[e][n]
// BM=128, BN=64, BK=32 (K=4096 logical over e-blocks).
// 4 waves stacked in m, each 32x64 (2x4 frags). grid = (8, Mc/128)
// ------------------------------------------------------------------
__global__ __launch_bounds__(256)
void mix_mfma(const _Float16* __restrict__ hh, const _Float16* __restrict__ hl,
              const _Float16* __restrict__ w2h, const _Float16* __restrict__ w2l,
              const float* __restrict__ eb2, const float* __restrict__ rw,
              float* __restrict__ C, int Mc)
{
    __shared__ _Float16 Ah[4096], Al[4096], Bh[2048], Bl[2048];
    const int tid = threadIdx.x;
    const int l = tid & 63, w = tid >> 6;
    const int m0 = blockIdx.y << 7, n0 = blockIdx.x << 6;
    const int kb = l >> 4, lr = l & 15;

    int aoff[2], boff[4];
    #pragma unroll
    for (int i = 0; i < 2; ++i) aoff[i] = (kb * 128 + w * 32 + i * 16 + lr) * 8;
    #pragma unroll
    for (int j = 0; j < 4; ++j) boff[j] = (kb * 64 + j * 16 + lr) * 8;

    f32x4 acc[2][4];
    #pragma unroll
    for (int i = 0; i < 2; ++i)
        #pragma unroll
        for (int j = 0; j < 4; ++j)
            acc[i][j] = (f32x4){0.f, 0.f, 0.f, 0.f};

    const int wbase = tid & 192;

    for (int k0 = 0; k0 < 4096; k0 += 32) {
        const int e = k0 >> 9, koff = k0 & 511;
        #pragma unroll
        for (int j = 0; j < 2; ++j) {
            const int c = (j << 8) + tid;
            const int ckb = c >> 7, cm = c & 127;
            const int lofs = ((j << 8) + wbase) * 8;
            const size_t ga = (((size_t)e * Mc + m0 + cm) << 9) + koff + ckb * 8;
            gload16(hh + ga, (void*)(Ah + lofs));
            gload16(hl + ga, (void*)(Al + lofs));
        }
        {
            const int ckb = tid >> 6, cn = tid & 63;
            const int lofs = wbase * 8;
            const size_t gb = ((size_t)((e << 6) + (koff >> 3) + ckb) * 512 + n0 + cn) * 8;
            gload16(w2h + gb, (void*)(Bh + lofs));
            gload16(w2l + gb, (void*)(Bl + lofs));
        }
        __syncthreads();
        f16x8 fah[2], fal[2], fbh[4], fbl[4];
        #pragma unroll
        for (int i = 0; i < 2; ++i) {
            fah[i] = *(const f16x8*)(Ah + aoff[i]);
            fal[i] = *(const f16x8*)(Al + aoff[i]);
        }
        #pragma unroll
        for (int j = 0; j < 4; ++j) {
            fbh[j] = *(const f16x8*)(Bh + boff[j]);
            fbl[j] = *(const f16x8*)(Bl + boff[j]);
        }
        #pragma unroll
        for (int i = 0; i < 2; ++i)
            #pragma unroll
            for (int j = 0; j < 4; ++j) {
                acc[i][j] = __builtin_amdgcn_mfma_f32_16x16x32_f16(fah[i], fbh[j], acc[i][j], 0, 0, 0);
                acc[i][j] = __builtin_amdgcn_mfma_f32_16x16x32_f16(fah[i], fbl[j], acc[i][j], 0, 0, 0);
                acc[i][j] = __builtin_amdgcn_mfma_f32_16x16x32_f16(fal[i], fbh[j], acc[i][j], 0, 0, 0);
            }
        __syncthreads();
    }
    #pragma unroll
    for (int i = 0; i < 2; ++i)
        #pragma unroll
        for (int j = 0; j < 4; ++j)
            #pragma unroll
            for (int r = 0; r < 4; ++r) {
                const int m = m0 + w * 32 + i * 16 + (l >> 4) * 4 + r;
                const int n = n0 + j * 16 + lr;
                float v = acc[i][j][r];
                #pragma unroll
                for (int e = 0; e < 8; ++e)
                    v = fmaf(rw[(m << 3) + e], eb2[(e << 9) + n], v);
                C[((size_t)m << 9) + n] = v;
            }
}

// ------------------------------------------------------------------
// fp32 tiled GEMM (projection / router-hidden / score-hidden)
// ------------------------------------------------------------------
template<int ACT>
__global__ __launch_bounds__(256)
void gemm64(const float* __restrict__ A, int lda,
            const float* __restrict__ B, int ldb,
            const float* __restrict__ bias,
            float* __restrict__ C, int ldc, int K)
{
    __shared__ float As[16][68];
    __shared__ float Bs[16][68];
    const int tid = threadIdx.x;
    const int tx = tid & 15, ty = tid >> 4;
    const int m0 = blockIdx.y << 6, n0 = blockIdx.x << 6;
    const int lm = tid >> 2, lk = (tid & 3) << 2;
    const int bk = tid >> 4, bn = (tid & 15) << 2;

    float acc[4][4] = {};
    const float* Ap = A + (size_t)(m0 + lm) * lda + lk;
    const float* Bp = B + (size_t)bk * ldb + n0 + bn;

    for (int k0 = 0; k0 < K; k0 += 16) {
        float4 av = *(const float4*)(Ap + k0);
        float4 bv = *(const float4*)(Bp + (size_t)k0 * ldb);
        As[lk + 0][lm] = av.x; As[lk + 1][lm] = av.y;
        As[lk + 2][lm] = av.z; As[lk + 3][lm] = av.w;
        *(float4*)&Bs[bk][bn] = bv;
        __syncthreads();
        #pragma unroll
        for (int kk = 0; kk < 16; ++kk) {
            float4 a = *(const float4*)&As[kk][ty << 2];
            float4 b = *(const float4*)&Bs[kk][tx << 2];
            float ar[4] = {a.x, a.y, a.z, a.w};
            float br[4] = {b.x, b.y, b.z, b.w};
            #pragma unroll
            for (int i = 0; i < 4; ++i)
                #pragma unroll
                for (int j = 0; j < 4; ++j)
                    acc[i][j] = fmaf(ar[i], br[j], acc[i][j]);
        }
        __syncthreads();
    }
    #pragma unroll
    for (int i = 0; i < 4; ++i) {
        const int m = m0 + (ty << 2) + i;
        float4 o;
        #pragma unroll
        for (int j = 0; j < 4; ++j) {
            const int n = n0 + (tx << 2) + j;
            float v = acc[i][j] + bias[n];
            if (ACT) v = gelu_f(v);
            ((float*)&o)[j] = v;
        }
        *(float4*)&C[(size_t)m * ldc + n0 + (tx << 2)] = o;
    }
}

// ------------------------------------------------------------------
// Router softmax (fp32)
// ------------------------------------------------------------------
__global__ __launch_bounds__(256)
void router_kernel(const float* __restrict__ t,
                   const float* __restrict__ rw2,
                   const float* __restrict__ rb2,
                   float* __restrict__ route_w)
{
    __shared__ float s[512 * 9];
    const int tid = threadIdx.x;
    for (int idx = tid; idx < 4096; idx += 256)
        s[(idx >> 3) * 9 + (idx & 7)] = rw2[idx];
    __syncthreads();
    const int lane = tid & 63;
    const int tok = (blockIdx.x << 2) + (tid >> 6);
    const float* tp = t + ((size_t)tok << 9);
    float acc[8] = {};
    #pragma unroll
    for (int kq = 0; kq < 8; ++kq) {
        const int k = (kq << 6) + lane;
        const float tv = tp[k];
        #pragma unroll
        for (int e = 0; e < 8; ++e)
            acc[e] = fmaf(tv, s[k * 9 + e], acc[e]);
    }
    #pragma unroll
    for (int e = 0; e < 8; ++e)
        #pragma unroll
        for (int off = 32; off; off >>= 1)
            acc[e] += __shfl_xor(acc[e], off, 64);
    float mx = -1e30f;
    #pragma unroll
    for (int e = 0; e < 8; ++e) { acc[e] += rb2[e]; mx = fmaxf(mx, acc[e]); }
    float sum = 0.f;
    #pragma unroll
    for (int e = 0; e < 8; ++e) { acc[e] = expf(acc[e] - mx); sum += acc[e]; }
    const float inv = 1.0f / sum;
    if (lane == 0) {
        #pragma unroll
        for (int e = 0; e < 8; ++e) route_w[(tok << 3) + e] = acc[e] * inv;
    }
}

__global__ __launch_bounds__(256)
void score_kernel(const float* __restrict__ u,
                  const float* __restrict__ sw2,
                  const float* __restrict__ sb2,
                  float* __restrict__ mlog, int mod)
{
    const int tid = threadIdx.x;
    const int lane = tid & 63;
    const int tok = (blockIdx.x << 2) + (tid >> 6);
    const float* up = u + ((size_t)tok << 9);
    float acc = 0.f;
    #pragma unroll
    for (int kq = 0; kq < 8; ++kq) {
        const int k = (kq << 6) + lane;
        acc = fmaf(up[k], sw2[k], acc);
    }
    #pragma unroll
    for (int off = 32; off; off >>= 1) acc += __shfl_xor(acc, off, 64);
    if (lane == 0) mlog[(tok << 2) + mod] = acc + sb2[0];
}

__global__ __launch_bounds__(256)
void final_kernel(const float* __restrict__ mixedb,
                  const float* __restrict__ mlog,
                  const float* __restrict__ g,
                  const float* __restrict__ bta,
                  float* __restrict__ out)
{
    const int tok = blockIdx.x, tid = threadIdx.x;
    float v[4];
    #pragma unroll
    for (int m = 0; m < 4; ++m) v[m] = mlog[(tok << 2) + m];
    int i1 = 0;
    #pragma unroll
    for (int m = 1; m < 4; ++m) if (v[m] > v[i1]) i1 = m;
    int i2 = (i1 == 0) ? 1 : 0;
    for (int m = i2 + 1; m < 4; ++m) if (m != i1 && v[m] > v[i2]) i2 = m;
    const float e2 = expf(v[i2] - v[i1]);
    const float winv = 1.0f / (1.0f + e2);
    const float w1 = winv, w2 = e2 * winv;
    const float* p1 = mixedb + (((size_t)i1 * TOK + tok) << 9);
    const float* p2 = mixedb + (((size_t)i2 * TOK + tok) << 9);
    const int h0 = tid, h1 = tid + 256;
    const float c0 = w1 * p1[h0] + w2 * p2[h0];
    const float c1 = w1 * p1[h1] + w2 * p2[h1];
    float s = c0 + c1, sq = c0 * c0 + c1 * c1;
    #pragma unroll
    for (int off = 32; off; off >>= 1) {
        s += __shfl_xor(s, off, 64);
        sq += __shfl_xor(sq, off, 64);
    }
    __shared__ float red[8];
    const int wv = tid >> 6, ln = tid & 63;
    if (ln == 0) { red[wv] = s; red[4 + wv] = sq; }
    __syncthreads();
    s = red[0] + red[1] + red[2] + red[3];
    sq = red[4] + red[5] + red[6] + red[7];
    const float mu = s * (1.0f / 512.0f);
    const float var = sq * (1.0f / 512.0f) - mu * mu;
    const float r = 1.0f / sqrtf(var + 1e-5f);
    out[((size_t)tok << 9) + h0] = (c0 - mu) * r * g[h0] + bta[h0];
    out[((size_t)tok << 9) + h1] = (c1 - mu) * r * g[h1] + bta[h1];
}

extern "C" void kernel_launch(void* const* d_in, const int* in_sizes, int n_in,
                              void* d_out, int out_size, void* d_ws, size_t ws_size,
                              hipStream_t stream)
{
    (void)in_sizes; (void)n_in; (void)out_size;
    const float* ew1  = (const float*)d_in[12];
    const float* eb1  = (const float*)d_in[13];
    const float* ew2  = (const float*)d_in[14];
    const float* eb2  = (const float*)d_in[15];
    const float* rw1  = (const float*)d_in[16];
    const float* rb1  = (const float*)d_in[17];
    const float* rw2  = (const float*)d_in[18];
    const float* rb2  = (const float*)d_in[19];
    const float* sw1  = (const float*)d_in[20];
    const float* sb1  = (const float*)d_in[21];
    const float* sw2  = (const float*)d_in[22];
    const float* sb2  = (const float*)d_in[23];
    const float* ln_g = (const float*)d_in[24];
    const float* ln_b = (const float*)d_in[25];
    const int KD[4] = {1024, 64, 768, 512};

    // ---- workspace layout (256B-aligned chunks) ----
    char* p = (char*)d_ws;
    auto alloc = [&](size_t bytes) {
        void* r = (void*)p;
        p += (bytes + 255) & ~(size_t)255;
        return r;
    };
    float*     mixedb  = (float*)alloc((size_t)4 * TOK * HD * 4);
    float*     x       = (float*)alloc((size_t)TOK * HD * 4);
    float*     scratch = (float*)alloc((size_t)TOK * HD * 4);
    float*     route_w = (float*)alloc((size_t)TOK * 8 * 4);
    float*     mlog    = (float*)alloc((size_t)TOK * 4 * 4);
    _Float16*  xh      = (_Float16*)alloc((size_t)TOK * HD * 2);
    _Float16*  xl      = (_Float16*)alloc((size_t)TOK * HD * 2);
    _Float16*  w1h     = (_Float16*)alloc((size_t)8 * HD * HD * 2);
    _Float16*  w1l     = (_Float16*)alloc((size_t)8 * HD * HD * 2);
    _Float16*  w2h     = (_Float16*)alloc((size_t)8 * HD * HD * 2);
    _Float16*  w2l     = (_Float16*)alloc((size_t)8 * HD * HD * 2);
    const size_t fixed_bytes = (size_t)(p - (char*)d_ws);

    // expert-chunk size Mc: h hi/lo needs Mc*8*HD*2*2 bytes
    int Mc = 256;
    const int cands[5] = {4096, 2048, 1024, 512, 256};
    for (int ci = 0; ci < 5; ++ci) {
        if (fixed_bytes + (size_t)cands[ci] * 8 * HD * 4 + 512 <= ws_size) { Mc = cands[ci]; break; }
    }
    _Float16* hh = (_Float16*)alloc((size_t)Mc * 8 * HD * 2);
    _Float16* hl = (_Float16*)alloc((size_t)Mc * 8 * HD * 2);

    // ---- weight prep (once) ----
    split_w_kernel<<<dim3(1024), 256, 0, stream>>>(ew1, w1h, w1l);
    split_w_kernel<<<dim3(1024), 256, 0, stream>>>(ew2, w2h, w2l);

    for (int mod = 0; mod < 4; ++mod) {
        const float* feat = (const float*)d_in[mod * 3 + 0];
        const float* pw   = (const float*)d_in[mod * 3 + 1];
        const float* pb   = (const float*)d_in[mod * 3 + 2];
        float* mixm = mixedb + (size_t)mod * TOK * HD;

        // x = feat @ pw + pb  (fp32)
        gemm64<0><<<dim3(HD / 64, TOK / 64), 256, 0, stream>>>(
            feat, KD[mod], pw, HD, pb, x, HD, KD[mod]);
        // x split for MFMA
        split_x_kernel<<<dim3(TOK * HD / 8 / 256), 256, 0, stream>>>(x, xh, xl);
        // t = gelu(x @ rw1 + rb1)
        gemm64<1><<<dim3(HD / 64, TOK / 64), 256, 0, stream>>>(
            x, HD, rw1, HD, rb1, scratch, HD, HD);
        // route_w = softmax(t @ rw2 + rb2)
        router_kernel<<<dim3(TOK / 4), 256, 0, stream>>>(scratch, rw2, rb2, route_w);
        // experts, chunked over tokens
        for (int c0 = 0; c0 < TOK; c0 += Mc) {
            expert_h_mfma<<<dim3(HD / 128, Mc / 128, 8), 256, 0, stream>>>(
                xh + ((size_t)c0 << 9), xl + ((size_t)c0 << 9), w1h, w1l,
                eb1, route_w + ((size_t)c0 << 3), hh, hl, Mc);
            mix_mfma<<<dim3(HD / 64, Mc / 128), 256, 0, stream>>>(
                hh, hl, w2h, w2l, eb2, route_w + ((size_t)c0 << 3),
                mixm + ((size_t)c0 << 9), Mc);
        }
        // u = gelu(mixed @ sw1 + sb1)
        gemm64<1><<<dim3(HD / 64, TOK / 64), 256, 0, stream>>>(
            mixm, HD, sw1, HD, sb1, scratch, HD, HD);
        // mlog[:,mod] = u @ sw2 + sb2
        score_kernel<<<dim3(TOK / 4), 256, 0, stream>>>(scratch, sw2, sb2, mlog, mod);
    }
    final_kernel<<<dim3(TOK), 256, 0, stream>>>(mixedb, mlog, ln_g, ln_b, (float*)d_out);
}